// Round 1
// 3474.932 us; speedup vs baseline: 1.1258x; 1.1258x over previous
//
#include <hip/hip_runtime.h>
#include <hip/hip_bf16.h>
#include <hip/hip_cooperative_groups.h>

namespace cg = cooperative_groups;

typedef __bf16 bf16_t;
typedef __bf16 bf16x8 __attribute__((ext_vector_type(8)));
typedef float f32x4 __attribute__((ext_vector_type(4)));

#define MFMA16x16x32(a, b, c) __builtin_amdgcn_mfma_f32_16x16x32_bf16((a), (b), (c), 0, 0, 0)

#define B_ 32
#define T_ 64
#define H_ 1024
#define E_ 512
#define V_ 32000
#define H3 3072
#define MROWS 2048  // B*T
#define LOGITS_SZ ((size_t)MROWS * V_)

// ---------------- transpose + fp32->bf16 convert: out[C][R] = (bf16) in[R][C]
__global__ __launch_bounds__(256) void k_transpose_bf16(
    const float* __restrict__ in, bf16_t* __restrict__ out, int R, int C) {
  __shared__ float tile[32][33];
  int c0 = blockIdx.x * 32, r0 = blockIdx.y * 32;
  int tx = threadIdx.x & 31, ty = threadIdx.x >> 5;
#pragma unroll
  for (int i = 0; i < 4; ++i) {
    int r = ty + i * 8;
    tile[r][tx] = in[(size_t)(r0 + r) * C + (c0 + tx)];
  }
  __syncthreads();
#pragma unroll
  for (int i = 0; i < 4; ++i) {
    int r = ty + i * 8;
    out[(size_t)(c0 + r) * R + (r0 + tx)] = (bf16_t)tile[tx][r];
  }
}

// ---------------- build A0 = bf16 [2048][1536] rows: [emb[X[b,t]] | h0[1][b]]
__global__ __launch_bounds__(256) void k_build_A0(
    const int* __restrict__ X, const float* __restrict__ emb,
    const float* __restrict__ h0, bf16_t* __restrict__ A0) {
  int idx = blockIdx.x * 256 + threadIdx.x;  // over 2048*1536
  int row = idx / (E_ + H_);
  int c = idx - row * (E_ + H_);
  float v;
  if (c < E_) {
    int tok = X[row];
    v = emb[(size_t)tok * E_ + c];
  } else {
    int b = row >> 6;  // row = b*T + t
    v = h0[(size_t)B_ * H_ + (size_t)b * H_ + (c - E_)];
  }
  A0[idx] = (bf16_t)v;
}

// ---------------- init hidden-state buffers from h0
__global__ __launch_bounds__(256) void k_init_h(
    const float* __restrict__ h0, float* __restrict__ h1f, bf16_t* __restrict__ h1b,
    float* __restrict__ h2f, bf16_t* __restrict__ h2b) {
  int i = blockIdx.x * 256 + threadIdx.x;  // < 32768
  float a = h0[i], b = h0[B_ * H_ + i];
  h1f[i] = a; h1b[i] = (bf16_t)a;
  h2f[i] = b; h2b[i] = (bf16_t)b;
}

// ---------------- generic bf16 MFMA GEMM: out[M][N] = A[M][K] @ BT[N][K]^T + bias[N]
__global__ __launch_bounds__(256) void k_gemm(
    const bf16_t* __restrict__ A, const bf16_t* __restrict__ BT,
    const float* __restrict__ bias, float* __restrict__ out,
    int M, int N, int K) {
  __shared__ bf16_t Asm[64][40];
  __shared__ bf16_t Bsm[64][40];
  int tid = threadIdx.x;
  int m0 = blockIdx.x * 64, n0 = blockIdx.y * 64;
  int lane = tid & 63, w = tid >> 6;
  int lr = lane & 15, q = lane >> 4;
  int wm = w & 1, wn = w >> 1;
  int srow = tid >> 2, sseg = (tid & 3) * 8;
  f32x4 acc[2][2] = {};
  const bf16_t* Ap = A + (size_t)(m0 + srow) * K + sseg;
  const bf16_t* Bp = BT + (size_t)(n0 + srow) * K + sseg;
  for (int kc = 0; kc < K; kc += 32) {
    *(bf16x8*)&Asm[srow][sseg] = *(const bf16x8*)(Ap + kc);
    *(bf16x8*)&Bsm[srow][sseg] = *(const bf16x8*)(Bp + kc);
    __syncthreads();
#pragma unroll
    for (int sm = 0; sm < 2; ++sm) {
      bf16x8 af = *(const bf16x8*)&Asm[wm * 32 + sm * 16 + lr][q * 8];
#pragma unroll
      for (int sn = 0; sn < 2; ++sn) {
        bf16x8 bfr = *(const bf16x8*)&Bsm[wn * 32 + sn * 16 + lr][q * 8];
        acc[sm][sn] = MFMA16x16x32(af, bfr, acc[sm][sn]);
      }
    }
    __syncthreads();
  }
#pragma unroll
  for (int sm = 0; sm < 2; ++sm)
#pragma unroll
    for (int sn = 0; sn < 2; ++sn) {
      int gr = m0 + wm * 32 + sm * 16 + q * 4;
      int gc = n0 + wn * 32 + sn * 16 + lr;
      float bb = bias[gc];
#pragma unroll
      for (int r = 0; r < 4; ++r)
        out[(size_t)(gr + r) * N + gc] = acc[sm][sn][r] + bb;
    }
}

// ---------------- persistent cooperative recurrence kernel
// 64 blocks x 256 threads. Blocks 0..31: layer0 (t = ph). Blocks 32..63: layer1
// (t = ph - 1). 65 phases, one grid.sync() per phase. Software-pipelined:
// layer0(t+1) runs concurrently with layer1(t). Per-wave fragment pattern and
// op order identical to the previous k_step0/k_step1 (bit-identical numerics).
struct RecurArgs {
  const bf16_t* U0T;
  const bf16_t* W1T;
  const bf16_t* U1T;
  const float* gx0;
  const float* b0h;  // b0 + H3
  const float* b1x;  // b1
  const float* b1h;  // b1 + H3
  float* h1f0; float* h1f1; float* h2f0; float* h2f1;
  bf16_t* h1b0; bf16_t* h1b1; bf16_t* h2b0; bf16_t* h2b1;
  bf16_t* seqb;
};

__global__ __launch_bounds__(256) void k_recur(RecurArgs a) {
  cg::grid_group grid = cg::this_grid();
  const int tid = threadIdx.x, lane = tid & 63, w = tid >> 6;
  const int lr = lane & 15, q = lane >> 4;
  const int blk = blockIdx.x;
  const bool is_l1 = blk >= 32;

  // chunk id within the layer: 0..127  (2 m-tiles x 64 i-groups)
  const int c = (blk & 31) * 4 + w;
  const int wm = c & 1;
  const int ig = c >> 1;
  const int i = ig * 16 + lr;

  // loop-invariant weight row pointers (per-wave slice stays L2-resident)
  const bf16_t* Bz = a.U0T + (size_t)i * H_ + q * 8;
  const bf16_t* Br = Bz + (size_t)H_ * H_;
  const bf16_t* Bh = Br + (size_t)H_ * H_;
  const bf16_t* Wz = a.W1T + (size_t)i * H_ + q * 8;
  const bf16_t* Wr = Wz + (size_t)H_ * H_;
  const bf16_t* Wh = Wr + (size_t)H_ * H_;
  const bf16_t* Uz = a.U1T + (size_t)i * H_ + q * 8;
  const bf16_t* Ur = Uz + (size_t)H_ * H_;
  const bf16_t* Uh = Ur + (size_t)H_ * H_;

  for (int ph = 0; ph < 65; ++ph) {
    if (!is_l1) {
      // ---- layer 0, t = ph: gh = h1 @ U0; gates with precomputed gx0
      int t = ph;
      if (t < 64) {
        int p = t & 1;
        const bf16_t* h1b_c = p ? a.h1b1 : a.h1b0;
        const float*  h1f_c = p ? a.h1f1 : a.h1f0;
        float*  h1f_n = p ? a.h1f0 : a.h1f1;
        bf16_t* h1b_n = p ? a.h1b0 : a.h1b1;
        const bf16_t* Ap = h1b_c + (size_t)(wm * 16 + lr) * H_ + q * 8;
        f32x4 az = {0.f, 0.f, 0.f, 0.f}, ar = {0.f, 0.f, 0.f, 0.f}, ah = {0.f, 0.f, 0.f, 0.f};
        for (int kc = 0; kc < H_; kc += 32) {
          bf16x8 af = *(const bf16x8*)(Ap + kc);
          az = MFMA16x16x32(af, *(const bf16x8*)(Bz + kc), az);
          ar = MFMA16x16x32(af, *(const bf16x8*)(Br + kc), ar);
          ah = MFMA16x16x32(af, *(const bf16x8*)(Bh + kc), ah);
        }
        float bz = a.b0h[i], br = a.b0h[H_ + i], bhh = a.b0h[2 * H_ + i];
#pragma unroll
        for (int r = 0; r < 4; ++r) {
          int b = wm * 16 + q * 4 + r;
          const float* gx = a.gx0 + (size_t)(b * T_ + t) * H3;
          float z  = 1.f / (1.f + __expf(-(gx[i] + az[r] + bz)));
          float rg = 1.f / (1.f + __expf(-(gx[H_ + i] + ar[r] + br)));
          float hc = tanhf(gx[2 * H_ + i] + rg * (ah[r] + bhh));
          float hold = h1f_c[b * H_ + i];
          float hn = z * hold + (1.f - z) * hc;
          h1f_n[b * H_ + i] = hn;
          h1b_n[b * H_ + i] = (bf16_t)hn;
        }
      }
    } else {
      // ---- layer 1, t = ph-1: gx = h1_new @ W1, gh = h2 @ U1
      int t = ph - 1;
      if (t >= 0) {
        int p = t & 1;
        const bf16_t* h1b_new = p ? a.h1b0 : a.h1b1;  // parity p^1 (written by layer0 at t)
        const bf16_t* h2b_c = p ? a.h2b1 : a.h2b0;
        const float*  h2f_c = p ? a.h2f1 : a.h2f0;
        float*  h2f_n = p ? a.h2f0 : a.h2f1;
        bf16_t* h2b_n = p ? a.h2b0 : a.h2b1;
        const bf16_t* A1 = h1b_new + (size_t)(wm * 16 + lr) * H_ + q * 8;
        const bf16_t* A2 = h2b_c + (size_t)(wm * 16 + lr) * H_ + q * 8;
        f32x4 xz = {0.f, 0.f, 0.f, 0.f}, xr = {0.f, 0.f, 0.f, 0.f}, xh = {0.f, 0.f, 0.f, 0.f};
        f32x4 hz = {0.f, 0.f, 0.f, 0.f}, hr = {0.f, 0.f, 0.f, 0.f}, hh = {0.f, 0.f, 0.f, 0.f};
        for (int kc = 0; kc < H_; kc += 32) {
          bf16x8 a1 = *(const bf16x8*)(A1 + kc);
          bf16x8 a2 = *(const bf16x8*)(A2 + kc);
          xz = MFMA16x16x32(a1, *(const bf16x8*)(Wz + kc), xz);
          xr = MFMA16x16x32(a1, *(const bf16x8*)(Wr + kc), xr);
          xh = MFMA16x16x32(a1, *(const bf16x8*)(Wh + kc), xh);
          hz = MFMA16x16x32(a2, *(const bf16x8*)(Uz + kc), hz);
          hr = MFMA16x16x32(a2, *(const bf16x8*)(Ur + kc), hr);
          hh = MFMA16x16x32(a2, *(const bf16x8*)(Uh + kc), hh);
        }
        float bxz = a.b1x[i], bxr = a.b1x[H_ + i], bxh = a.b1x[2 * H_ + i];
        float bhz = a.b1h[i], bhr = a.b1h[H_ + i], bhh = a.b1h[2 * H_ + i];
#pragma unroll
        for (int r = 0; r < 4; ++r) {
          int b = wm * 16 + q * 4 + r;
          float z  = 1.f / (1.f + __expf(-(xz[r] + bxz + hz[r] + bhz)));
          float rg = 1.f / (1.f + __expf(-(xr[r] + bxr + hr[r] + bhr)));
          float hc = tanhf(xh[r] + bxh + rg * (hh[r] + bhh));
          float hold = h2f_c[b * H_ + i];
          float hn = z * hold + (1.f - z) * hc;
          h2f_n[b * H_ + i] = hn;
          h2b_n[b * H_ + i] = (bf16_t)hn;
          a.seqb[(size_t)(b * T_ + t) * H_ + i] = (bf16_t)hn;
        }
      }
    }
    grid.sync();
  }
}

// ---------------- copy final states to output tail
__global__ __launch_bounds__(256) void k_final(
    const float* __restrict__ h1f, const float* __restrict__ h2f,
    float* __restrict__ out) {
  int i = blockIdx.x * 256 + threadIdx.x;  // < 32768
  out[LOGITS_SZ + i] = h1f[i];
  out[LOGITS_SZ + B_ * H_ + i] = h2f[i];
}

extern "C" void kernel_launch(void* const* d_in, const int* in_sizes, int n_in,
                              void* d_out, int out_size, void* d_ws, size_t ws_size,
                              hipStream_t stream) {
  const int*   X   = (const int*)d_in[0];
  const float* h0  = (const float*)d_in[1];
  const float* emb = (const float*)d_in[2];
  const float* W0  = (const float*)d_in[3];
  const float* U0  = (const float*)d_in[4];
  const float* b0  = (const float*)d_in[5];
  const float* W1  = (const float*)d_in[6];
  const float* U1  = (const float*)d_in[7];
  const float* b1  = (const float*)d_in[8];
  const float* Wd  = (const float*)d_in[9];
  const float* bd  = (const float*)d_in[10];
  float* out = (float*)d_out;

  // workspace layout (~130.3 MB)
  char* p = (char*)d_ws;
  bf16_t* W0T = (bf16_t*)p; p += (size_t)H3 * (E_ + H_) * 2;
  bf16_t* U0T = (bf16_t*)p; p += (size_t)H3 * H_ * 2;
  bf16_t* W1T = (bf16_t*)p; p += (size_t)H3 * H_ * 2;
  bf16_t* U1T = (bf16_t*)p; p += (size_t)H3 * H_ * 2;
  bf16_t* WdT = (bf16_t*)p; p += (size_t)V_ * H_ * 2;
  bf16_t* A0  = (bf16_t*)p; p += (size_t)MROWS * (E_ + H_) * 2;
  bf16_t* seqb = (bf16_t*)p; p += (size_t)MROWS * H_ * 2;
  float* gx0 = (float*)p; p += (size_t)MROWS * H3 * 4;
  float* h1f[2], * h2f[2];
  bf16_t* h1b[2], * h2b[2];
  h1f[0] = (float*)p; p += B_ * H_ * 4;
  h1f[1] = (float*)p; p += B_ * H_ * 4;
  h2f[0] = (float*)p; p += B_ * H_ * 4;
  h2f[1] = (float*)p; p += B_ * H_ * 4;
  h1b[0] = (bf16_t*)p; p += B_ * H_ * 2;
  h1b[1] = (bf16_t*)p; p += B_ * H_ * 2;
  h2b[0] = (bf16_t*)p; p += B_ * H_ * 2;
  h2b[1] = (bf16_t*)p; p += B_ * H_ * 2;

  // weight transposes -> bf16 [N][K]
  k_transpose_bf16<<<dim3(H3 / 32, (E_ + H_) / 32), 256, 0, stream>>>(W0, W0T, E_ + H_, H3);
  k_transpose_bf16<<<dim3(H3 / 32, H_ / 32), 256, 0, stream>>>(U0, U0T, H_, H3);
  k_transpose_bf16<<<dim3(H3 / 32, H_ / 32), 256, 0, stream>>>(W1, W1T, H_, H3);
  k_transpose_bf16<<<dim3(H3 / 32, H_ / 32), 256, 0, stream>>>(U1, U1T, H_, H3);
  k_transpose_bf16<<<dim3(V_ / 32, H_ / 32), 256, 0, stream>>>(Wd, WdT, H_, V_);

  k_build_A0<<<(MROWS * (E_ + H_)) / 256, 256, 0, stream>>>(X, emb, h0, A0);
  k_init_h<<<(B_ * H_) / 256, 256, 0, stream>>>(h0, h1f[0], h1b[0], h2f[0], h2b[0]);

  // gx0 = dec_in @ W0 + b0[0]  (all timesteps at once)
  k_gemm<<<dim3(MROWS / 64, H3 / 64), 256, 0, stream>>>(A0, W0T, b0, gx0, MROWS, H3, E_ + H_);

  // sequential recurrence: one persistent cooperative kernel, 65 pipelined phases
  RecurArgs ra;
  ra.U0T = U0T; ra.W1T = W1T; ra.U1T = U1T;
  ra.gx0 = gx0; ra.b0h = b0 + H3; ra.b1x = b1; ra.b1h = b1 + H3;
  ra.h1f0 = h1f[0]; ra.h1f1 = h1f[1]; ra.h2f0 = h2f[0]; ra.h2f1 = h2f[1];
  ra.h1b0 = h1b[0]; ra.h1b1 = h1b[1]; ra.h2b0 = h2b[0]; ra.h2b1 = h2b[1];
  ra.seqb = seqb;
  void* kargs[] = {&ra};
  hipLaunchCooperativeKernel((const void*)k_recur, dim3(64), dim3(256), kargs, 0, stream);

  // logits = seq @ Wd + bd
  k_gemm<<<dim3(MROWS / 64, V_ / 64), 256, 0, stream>>>(seqb, WdT, bd, out, MROWS, V_, H_);

  k_final<<<(B_ * H_) / 256, 256, 0, stream>>>(h1f[0], h2f[0], out);
}